// Round 16
// baseline (156.644 us; speedup 1.0000x reference)
//
#include <hip/hip_runtime.h>

// WeightedAggregator: out[n,:] = sum_{e in seg(n)} eff_w[e]*feat[nidx[e],:] / den[n]
//   wsum[n] = sum of edge_weights in segment n (segment_ids sorted)
//   use_mean = (wsum == 0) -> eff_w = 1, den = deg; else eff_w = w, den = wsum
//   den == 0 -> 1 (empty nodes output zeros)
//
// R15 post-mortem: R9 quarter-wave (4-in-flight, stragglers) = 67us; R8
// (16-in-flight, shfl) = 62us; both ~3.2 TB/s on 183MB -> random-gather
// plateau suspected. R16: full wave per node, ONE LANE PER DIM:
//  - each row gather = 64 lanes x 4B = one coalesced 256B instruction
//  - idx/w are wave-uniform broadcast loads; ws replicated in every lane
//  - dual accumulators defer use_mean; zero cross-lane ops, zero ballots
//  - deg is wave-uniform -> no divergence, no stragglers
//  - manual unroll-8 -> 8 independent idx->row chains (2KB in flight/wave)

#define D_FEAT 64

// ---- Pass 1: offs[v] = lower_bound(seg, v), v in [0, N] -------------------
__global__ __launch_bounds__(256) void WA_build_offsets_kernel(
        const int* __restrict__ seg, int* __restrict__ offs, int N, int E) {
    const int tid = blockIdx.x * blockDim.x + threadIdx.x;
    if (tid > E) return;
    const int cur  = (tid == E) ? N : seg[tid];
    const int prev = (tid == 0) ? -1 : seg[tid - 1];
    // Only boundary threads loop; avg trip = N/E + 1 ~ 1.06.
    for (int v = prev + 1; v <= cur; ++v) offs[v] = tid;
}

// ---- Pass 2: one wave per node, one lane per feature dim ------------------
__global__ __launch_bounds__(256) void WeightedAggregator_28424093564968_kernel(
        const float* __restrict__ feat,   // [N, 64]
        const float* __restrict__ ew,     // [E]
        const int*   __restrict__ nidx,   // [E]
        const int*   __restrict__ offs,   // [N+1]
        float*       __restrict__ out,    // [N, 64]
        int N) {
    const int wave = (blockIdx.x * blockDim.x + threadIdx.x) >> 6;
    const int lane = threadIdx.x & 63;    // this lane's feature dim
    if (wave >= N) return;

    const int start = offs[wave];
    const int end   = offs[wave + 1];
    const int deg   = end - start;

    float ws = 0.0f;   // replicated identically across all 64 lanes
    float aw = 0.0f;   // weighted feature sum (this lane's dim)
    float au = 0.0f;   // unweighted feature sum

    int e = start;
    // Main body: 8 independent (idx -> row) load chains in flight.
    for (; e + 8 <= end; e += 8) {
        #pragma unroll
        for (int j = 0; j < 8; ++j) {
            const int   id = nidx[e + j];                       // uniform bcast
            const float w  = ew[e + j];                         // uniform bcast
            const float f  = feat[(size_t)id * D_FEAT + lane];  // 256B row
            ws += w;
            aw += w * f;
            au += f;
        }
    }
    for (; e < end; ++e) {
        const int   id = nidx[e];
        const float w  = ew[e];
        const float f  = feat[(size_t)id * D_FEAT + lane];
        ws += w;
        aw += w * f;
        au += f;
    }

    const bool use_mean = (ws == 0.0f);
    float den = use_mean ? (float)deg : ws;
    if (den == 0.0f) den = 1.0f;

    out[(size_t)wave * D_FEAT + lane] = (use_mean ? au : aw) / den;
}

// ---- Fallback (ws too small): R6's search-based kernel --------------------
__global__ __launch_bounds__(256) void WA_search_kernel(
        const float* __restrict__ feat, const float* __restrict__ ew,
        const int* __restrict__ nidx, const int* __restrict__ seg,
        float* __restrict__ out, int N, int E) {
    const int wave = (blockIdx.x * blockDim.x + threadIdx.x) >> 6;
    const int lane = threadIdx.x & 63;
    if (wave >= N) return;
    const int n = wave;

    int lo = 0, hi = E;
    while (hi - lo > 64) {
        const long long span = hi - lo;
        const int p = lo + (int)((span * (lane + 1)) / 65);
        const bool ge = seg[p] >= n;
        const unsigned long long mask = __ballot(ge);
        if (mask == 0ull) {
            lo = lo + (int)((span * 64) / 65);
        } else {
            const int first = __ffsll((long long)mask) - 1;
            const int nhi = lo + (int)((span * (first + 1)) / 65);
            const int nlo = (first == 0) ? lo : lo + (int)((span * first) / 65);
            lo = nlo; hi = nhi;
        }
    }
    {
        const int p = lo + lane;
        const bool ge = (p >= hi) || (seg[p] >= n);
        const unsigned long long mask = __ballot(ge);
        lo = (mask == 0ull) ? hi : lo + __ffsll((long long)mask) - 1;
    }
    const int start = lo;
    int end = start;
    for (;;) {
        const int p = end + lane;
        const bool stop = (p >= E) || (seg[p] > n);
        const unsigned long long mask = __ballot(stop);
        if (mask) { end += __ffsll((long long)mask) - 1; break; }
        end += 64;
    }

    float ws = 0.0f;
    for (int e = start + lane; e < end; e += 64) ws += ew[e];
    #pragma unroll
    for (int off = 32; off > 0; off >>= 1) ws += __shfl_xor(ws, off);
    const bool use_mean = (ws == 0.0f);
    float den = use_mean ? (float)(end - start) : ws;
    if (den == 0.0f) den = 1.0f;

    float aw = 0.0f;
    for (int e = start; e < end; ++e) {
        const int   id = nidx[e];
        const float w  = use_mean ? 1.0f : ew[e];
        aw += w * feat[(size_t)id * D_FEAT + lane];
    }
    out[(size_t)n * D_FEAT + lane] = aw / den;
}

extern "C" void kernel_launch(void* const* d_in, const int* in_sizes, int n_in,
                              void* d_out, int out_size, void* d_ws, size_t ws_size,
                              hipStream_t stream) {
    const float* feat = (const float*)d_in[0];
    const float* ew   = (const float*)d_in[1];
    const int*   nidx = (const int*)d_in[2];
    const int*   seg  = (const int*)d_in[3];
    float*       out  = (float*)d_out;

    const int E = in_sizes[1];
    const int N = in_sizes[0] / D_FEAT;

    // One wave per node, 4 waves per 256-thread block.
    const int grid = (N + 3) / 4;

    if (ws_size >= (size_t)(N + 1) * sizeof(int)) {
        int* offs = (int*)d_ws;
        const int g1 = (E + 1 + 255) / 256;
        WA_build_offsets_kernel<<<g1, 256, 0, stream>>>(seg, offs, N, E);
        WeightedAggregator_28424093564968_kernel<<<grid, 256, 0, stream>>>(
            feat, ew, nidx, offs, out, N);
    } else {
        WA_search_kernel<<<grid, 256, 0, stream>>>(feat, ew, nidx, seg, out, N, E);
    }
}